// Round 5
// baseline (501.626 us; speedup 1.0000x reference)
//
#include <hip/hip_runtime.h>
#include <cstdint>

// R11 = R8's verified fused kernel + depth-2 prefetch, with the barrier
// expressed as IR-level LDS-only fences instead of inline asm.
// R9/R10 post-mortem: the asm s_waitcnt + "memory" clobber + sched_barrier(0)
// combo caused a ~1GB scratch fill/spill storm (WRITE 29->664MB, FETCH
// 131->621MB, 4x slowdown) in BOTH lambda and macro forms -> the asm path is
// the poison (m141 pathology), not the pipeline idea. R8's real stall: at the
// ds_write, loads have had only ~1.2us flight vs ~2.6us transfer (at barrier
// time vmcnt is already 0 -- __syncthreads' drain was free). Fix: depth-2
// named register sets (flight ~2 phases, compiler auto-emits counted
// vmcnt(4) at each ds_write), and a barrier that orders ONLY LDS:
//   fence(release,"workgroup","local"); s_barrier; fence(acquire,...)
// = __syncthreads minus the vmcnt drain, fully visible to regalloc/scheduler.
// Everything else (layout, XOR swizzle, compute body, reduction, kWTA) is
// bit-identical to the verified R8.

typedef float vf4 __attribute__((ext_vector_type(4)));
typedef float vf2 __attribute__((ext_vector_type(2)));

#define RFN 512
#define TN  32
#define KN  32
#define LN  2048
#define CHUNK 128
#define NITER (LN / CHUNK)   // 16

// LDS-only barrier: orders ds ops across the workgroup (lgkmcnt), leaves
// vmcnt counted so in-flight NT prefetch loads survive the barrier.
#define BARW() do {                                                  \
    __builtin_amdgcn_fence(__ATOMIC_RELEASE, "workgroup", "local");  \
    __builtin_amdgcn_s_barrier();                                    \
    __builtin_amdgcn_fence(__ATOMIC_ACQUIRE, "workgroup", "local");  \
} while (0)

// R8's verified compute body (macro-inlined; R10 proved the macro compiles
// to the identical LDS/FMA structure -- same bank-conflict count as R8).
#define COMPUTE(BUF) do {                                                        \
    const float* rs_  = (BUF);                                                   \
    const float* wsh_ = (BUF) + 32 * CHUNK;                                      \
    _Pragma("unroll")                                                            \
    for (int q = 0; q < 4; ++q) {                                                \
        const int qg = (wv << 2) + q;            /* this wave's l-quad */        \
        vf4 a[4], b[4];                                                          \
        _Pragma("unroll")                                                        \
        for (int j = 0; j < 4; ++j) {                                            \
            const int row = tg + 8 * j;                                          \
            a[j] = *(const vf4*)(rs_ + row * CHUNK + ((qg ^ (row & 31)) << 2));  \
        }                                                                        \
        _Pragma("unroll")                                                        \
        for (int j = 0; j < 4; ++j) {                                            \
            const int row = kg + 8 * j;   /* stored at 32+row; (32+row)&31==row */\
            b[j] = *(const vf4*)(wsh_ + row * CHUNK + ((qg ^ (row & 31)) << 2)); \
        }                                                                        \
        _Pragma("unroll")                                                        \
        for (int jt = 0; jt < 4; ++jt)                                           \
            _Pragma("unroll")                                                    \
            for (int jk = 0; jk < 4; ++jk) {                                     \
                float v0 = fmaf(a[jt].x, b[jk].x, acc[jt][jk]);                  \
                v0 = fmaf(a[jt].y, b[jk].y, v0);                                 \
                v0 = fmaf(a[jt].z, b[jk].z, v0);                                 \
                acc[jt][jk] = fmaf(a[jt].w, b[jk].w, v0);                        \
            }                                                                    \
    }                                                                            \
} while (0)

__global__ __launch_bounds__(512, 4) void column1_fused(
    const float* __restrict__ rec,   // (T=32, C=1, RF=512, L=2048)
    const float* __restrict__ wgt,   // (RF=512, K=32, C=1, L=2048)
    float* __restrict__ out)         // (T=32, 1, K=32, RF=512)
{
    __shared__ __align__(16) float lds[2 * 64 * CHUNK];  // 64 KB dbuf; tail reuses as red
    __shared__ float thr_s[32 * 33];
    __shared__ float nspk_s[32], vals_s[32], cand_s[32], tot_s[32], mask_s[32];

    const int r    = blockIdx.x;     // branch
    const int tid  = threadIdx.x;
    const int lane = tid & 63;
    const int wv   = tid >> 6;       // wave 0..7: splits chunk's 32 quads 8-ways
    const int tg   = lane >> 3;      // 0..7 : owns t in {tg, tg+8, tg+16, tg+24}
    const int kg   = lane & 7;       // 0..7 : owns k in {kg, kg+8, kg+16, kg+24}

    // ---- staging: 4 vf4/thread; rows r0+16s (0..31 rec-t, 32..63 wgt-k), quad c4
    const int c4 = tid & 31;         // quad within 128 floats
    const int r0 = tid >> 5;         // 0..15
    const float* g[4];               // single stream, steps +CHUNK per phase
    int ldoff[4];
#pragma unroll
    for (int s = 0; s < 4; ++s) {
        const int row = r0 + 16 * s;                // 0..63
        if (row < 32) g[s] = rec + ((size_t)(row * RFN + r)) * LN + (c4 << 2);
        else          g[s] = wgt + ((size_t)(r * KN + (row - 32))) * LN + (c4 << 2);
        // XOR swizzle: quad c4 stored at c4 ^ (row&31) -> conflict-free b128 reads, no pad
        ldoff[s] = row * CHUNK + ((c4 ^ (row & 31)) << 2);
    }

    // depth-2 register prefetch: statically named sets (rule #20)
    vf4 sA[4], sB[4];
#pragma unroll
    for (int s = 0; s < 4; ++s) {    // chunk 0
        sA[s] = __builtin_nontemporal_load((const vf4*)g[s]);
        g[s] += CHUNK;
    }
#pragma unroll
    for (int s = 0; s < 4; ++s) {    // chunk 1
        sB[s] = __builtin_nontemporal_load((const vf4*)g[s]);
        g[s] += CHUNK;
    }

    float acc[4][4];
#pragma unroll
    for (int jt = 0; jt < 4; ++jt)
#pragma unroll
        for (int jk = 0; jk < 4; ++jk) acc[jt][jk] = 0.0f;

    for (int it = 0; it < NITER; it += 2) {
        // ---- chunk it: buffer 0, register set A
        {
            float* buf = lds;
#pragma unroll
            for (int s = 0; s < 4; ++s) *(vf4*)(buf + ldoff[s]) = sA[s];  // dep-wait: counted vmcnt (sB stays in flight)
            BARW();
            if (it + 2 < NITER) {
#pragma unroll
                for (int s = 0; s < 4; ++s) {
                    sA[s] = __builtin_nontemporal_load((const vf4*)g[s]);  // chunk it+2
                    g[s] += CHUNK;
                }
            }
            COMPUTE(buf);
        }
        // ---- chunk it+1: buffer 1, register set B
        {
            float* buf = lds + 64 * CHUNK;
#pragma unroll
            for (int s = 0; s < 4; ++s) *(vf4*)(buf + ldoff[s]) = sB[s];  // dep-wait: counted vmcnt (sA stays in flight)
            BARW();
            if (it + 3 < NITER) {
#pragma unroll
                for (int s = 0; s < 4; ++s) {
                    sB[s] = __builtin_nontemporal_load((const vf4*)g[s]);  // chunk it+3
                    g[s] += CHUNK;
                }
            }
            COMPUTE(buf);
        }
    }

    __syncthreads();   // full drain fine here (once): last ds_reads done before red overwrite

    // ---- cross-wave reduction: 8 sets x 1024 floats = 32 KB into the dbuf region
    float* red = lds;
#pragma unroll
    for (int jt = 0; jt < 4; ++jt)
#pragma unroll
        for (int jk = 0; jk < 4; ++jk)
            red[(wv << 10) + (tg + 8 * jt) * 32 + (kg + 8 * jk)] = acc[jt][jk];
    __syncthreads();

    // ---- each thread sums 2 outputs over the 8 wave-sets, thresholds into thr_s
    const int o2 = tid << 1;                         // 0..1022, flat (t,k) = o2>>5, o2&31
    float pv0 = 0.0f, pv1 = 0.0f;
#pragma unroll
    for (int s = 0; s < 8; ++s) {
        vf2 p = *(const vf2*)(red + (s << 10) + o2);
        pv0 += p.x; pv1 += p.y;
    }
    {
        const float th0 = (pv0 > 20.0f) ? pv0 : 0.0f;  // sf.fire: strictly greater
        const float th1 = (pv1 > 20.0f) ? pv1 : 0.0f;
        thr_s[(o2 >> 5) * 33 + (o2 & 31)]             = th0;
        thr_s[((o2 + 1) >> 5) * 33 + ((o2 + 1) & 31)] = th1;
    }
    __syncthreads();

    // ---- kWTA (verified logic, unchanged)
    if (tid < 32) {
        const int k = tid;
        int ns = 0;
        for (int t = 0; t < 32; ++t) ns += (thr_s[t * 33 + k] > 0.0f) ? 1 : 0;
        int first = 32 - ns; if (first > 31) first = 31;   // clip(T - nspk, 0, T-1)
        const float vf = thr_s[first * 33 + k];
        nspk_s[k] = (float)ns;
        vals_s[k] = vf;
        cand_s[k] = (ns > 0) ? vf : 0.0f;                  // max_t spikes*vals per k
        mask_s[k] = 0.0f;
    }
    __syncthreads();

    if (tid == 0) {
        float vm = 0.0f;
        for (int k = 0; k < 32; ++k) vm = fmaxf(vm, cand_s[k]);
        const float v = vm * 32.0f;                        // trunc.max() * T
        for (int k = 0; k < 32; ++k) tot_s[k] = nspk_s[k] * (vals_s[k] + v);
        // top-4, ties -> lower index (matches lax.top_k); winner valid iff total != 0
        for (int sel = 0; sel < 4; ++sel) {
            int best = 0; float bv = -1.0f;
            for (int k = 0; k < 32; ++k) {
                const float tv = tot_s[k];
                if (tv > bv) { bv = tv; best = k; }
            }
            if (bv > 0.0f) mask_s[best] = 1.0f;
            tot_s[best] = -1.0f;
        }
    }
    __syncthreads();

#pragma unroll
    for (int e = 0; e < 2; ++e) {
        const int oo = o2 + e;
        const int t = oo >> 5, k = oo & 31;
        const float v = (thr_s[t * 33 + k] > 0.0f && mask_s[k] > 0.0f) ? 1.0f : 0.0f;
        __builtin_nontemporal_store(v, out + (size_t)t * (KN * RFN) + k * RFN + r);
    }
}

extern "C" void kernel_launch(void* const* d_in, const int* in_sizes, int n_in,
                              void* d_out, int out_size, void* d_ws, size_t ws_size,
                              hipStream_t stream) {
    const float* rec = (const float*)d_in[0];   // rec_field (32,1,512,2048)
    const float* wgt = (const float*)d_in[1];   // W         (512,32,1,2048)
    // d_in[2] = reward: unused by the forward output; d_ws: unused (fully fused)
    float* out = (float*)d_out;                 // (32,1,32,512)
    column1_fused<<<dim3(RFN), dim3(512), 0, stream>>>(rec, wgt, out);
}

// Round 7
// 313.272 us; speedup vs baseline: 1.6012x; 1.6012x over previous
//
#include <hip/hip_runtime.h>
#include <cstdint>

// R13 = R12 resubmit (round 6 failed with a container-level infra error; same
// failure mode as round 1, which was proven an infra flake when the identical
// kernel passed at round 2. Kernel audit found no hang mechanism: uniform
// barriers, static trip counts, legal global_load_lds (literal size=16,
// wave-uniform LDS dest, per-lane global src), __syncthreads provides the
// vmcnt drain the staging needs).
//
// R12: global_load_lds staging (m97 pattern) replaces register staging.
// R9/R10/R11 post-mortem: identical spill storms under BOTH asm-barrier and
// IR-fence variants -> depth-2 register sets were the poison, not the barrier.
// VGPR_Count pinned at 64 while spilling ~1KB/thread = the allocator targets
// 8 waves/EU (64-reg budget; launch_bounds' 2nd arg is a MINIMUM only, and
// the heuristic ignores the 70.6KB LDS cap). Fix is structural:
//  - __builtin_amdgcn_global_load_lds(16B): zero staging registers, no
//    ds_write; loads issued right after the barrier fly during the whole
//    LDS-bound compute phase (~2.56us >= 2.6us fair-share transfer).
//  - __syncthreads()' vmcnt(0)+lgkmcnt(0) drain before s_barrier is now
//    exactly the required semantics (stage complete => buffer ready). No asm.
//  - XOR swizzle kept via rule #21: LDS dest linear (HW: wave base+lane*16),
//    per-lane GLOBAL source pre-swizzled with the same involution
//    (q ^= row&31), so COMPUTE is bit-identical to verified R8.
//  - amdgpu_waves_per_eu(4,4): allocator budgets 128 VGPR, stops chasing
//    8 waves/EU (occupancy is LDS-capped at 4/EU = 2 blocks/CU anyway).

typedef float vf4 __attribute__((ext_vector_type(4)));
typedef float vf2 __attribute__((ext_vector_type(2)));

#define RFN 512
#define TN  32
#define KN  32
#define LN  2048
#define CHUNK 128
#define NITER (LN / CHUNK)   // 16

__device__ __forceinline__ void gload_lds16(const float* g, float* l) {
    __builtin_amdgcn_global_load_lds(
        (const __attribute__((address_space(1))) void*)g,
        (__attribute__((address_space(3))) void*)l, 16, 0, 0);
}

// R8's verified compute body (identical LDS layout & swizzle; R10/R11 proved
// the macro compiles to the same LDS/FMA structure -- same conflict count).
#define COMPUTE(BUF) do {                                                        \
    const float* rs_  = (BUF);                                                   \
    const float* wsh_ = (BUF) + 32 * CHUNK;                                      \
    _Pragma("unroll")                                                            \
    for (int q = 0; q < 4; ++q) {                                                \
        const int qg = (wv << 2) + q;            /* this wave's l-quad */        \
        vf4 a[4], b[4];                                                          \
        _Pragma("unroll")                                                        \
        for (int j = 0; j < 4; ++j) {                                            \
            const int row = tg + 8 * j;                                          \
            a[j] = *(const vf4*)(rs_ + row * CHUNK + ((qg ^ (row & 31)) << 2));  \
        }                                                                        \
        _Pragma("unroll")                                                        \
        for (int j = 0; j < 4; ++j) {                                            \
            const int row = kg + 8 * j;   /* stored at 32+row; (32+row)&31==row */\
            b[j] = *(const vf4*)(wsh_ + row * CHUNK + ((qg ^ (row & 31)) << 2)); \
        }                                                                        \
        _Pragma("unroll")                                                        \
        for (int jt = 0; jt < 4; ++jt)                                           \
            _Pragma("unroll")                                                    \
            for (int jk = 0; jk < 4; ++jk) {                                     \
                float v0 = fmaf(a[jt].x, b[jk].x, acc[jt][jk]);                  \
                v0 = fmaf(a[jt].y, b[jk].y, v0);                                 \
                v0 = fmaf(a[jt].z, b[jk].z, v0);                                 \
                acc[jt][jk] = fmaf(a[jt].w, b[jk].w, v0);                        \
            }                                                                    \
    }                                                                            \
} while (0)

// Stage one 32KB chunk into BUFBASE: 4 wave-level gload_lds per thread.
// Issue s of wave wv covers LDS rows {2i, 2i+1}, i = s*8+wv (1KB, linear).
// Per-lane global source is pre-swizzled; g[] advances +CHUNK per chunk.
#define STAGE(BUFBASE) do {                                                      \
    _Pragma("unroll")                                                            \
    for (int s = 0; s < 4; ++s) {                                                \
        gload_lds16(g[s], (BUFBASE) + (((s << 3) + wv) << 8));                   \
        g[s] += CHUNK;                                                           \
    }                                                                            \
} while (0)

__global__ __attribute__((amdgpu_waves_per_eu(4, 4))) __launch_bounds__(512)
void column1_fused(
    const float* __restrict__ rec,   // (T=32, C=1, RF=512, L=2048)
    const float* __restrict__ wgt,   // (RF=512, K=32, C=1, L=2048)
    float* __restrict__ out)         // (T=32, 1, K=32, RF=512)
{
    __shared__ __align__(16) float lds[2 * 64 * CHUNK];  // 64 KB dbuf; tail reuses as red
    __shared__ float thr_s[32 * 33];
    __shared__ float nspk_s[32], vals_s[32], cand_s[32], tot_s[32], mask_s[32];

    const int r    = blockIdx.x;     // branch
    const int tid  = threadIdx.x;
    const int lane = tid & 63;
    const int wv   = tid >> 6;       // wave 0..7
    const int tg   = lane >> 3;      // 0..7 : owns t in {tg, tg+8, tg+16, tg+24}
    const int kg   = lane & 7;       // 0..7 : owns k in {kg, kg+8, kg+16, kg+24}

    // ---- per-lane pre-swizzled global sources for the 4 staging issues.
    // Issue s: LDS rows {2i, 2i+1}, i = s*8+wv; lane writes LDS quad (lane&31)
    // of row 2i+(lane>>5), which must hold global quad (lane&31)^(row&31).
    const float* g[4];
#pragma unroll
    for (int s = 0; s < 4; ++s) {
        const int i    = (s << 3) + wv;
        const int row  = (i << 1) + (lane >> 5);        // 0..63
        const int qg   = (lane & 31) ^ (row & 31);      // swizzled source quad
        if (row < 32) g[s] = rec + ((size_t)(row * RFN + r)) * LN + (qg << 2);
        else          g[s] = wgt + ((size_t)(r * KN + (row - 32))) * LN + (qg << 2);
    }

    float acc[4][4];
#pragma unroll
    for (int jt = 0; jt < 4; ++jt)
#pragma unroll
        for (int jk = 0; jk < 4; ++jk) acc[jt][jk] = 0.0f;

    STAGE(lds);                      // chunk 0 -> buf0 (in flight)

    for (int it = 0; it < NITER; ++it) {
        float* buf = lds + (it & 1) * (64 * CHUNK);
        __syncthreads();             // drains own vmcnt: buf fully staged; other buf free
        if (it + 1 < NITER) STAGE(lds + ((it + 1) & 1) * (64 * CHUNK));  // fly during compute
        COMPUTE(buf);
    }

    __syncthreads();   // last ds_reads (buf1) done before red overwrites buf0 region

    // ---- cross-wave reduction: 8 sets x 1024 floats = 32 KB into the dbuf region
    float* red = lds;
#pragma unroll
    for (int jt = 0; jt < 4; ++jt)
#pragma unroll
        for (int jk = 0; jk < 4; ++jk)
            red[(wv << 10) + (tg + 8 * jt) * 32 + (kg + 8 * jk)] = acc[jt][jk];
    __syncthreads();

    // ---- each thread sums 2 outputs over the 8 wave-sets, thresholds into thr_s
    const int o2 = tid << 1;                         // 0..1022, flat (t,k) = o2>>5, o2&31
    float pv0 = 0.0f, pv1 = 0.0f;
#pragma unroll
    for (int s = 0; s < 8; ++s) {
        vf2 p = *(const vf2*)(red + (s << 10) + o2);
        pv0 += p.x; pv1 += p.y;
    }
    {
        const float th0 = (pv0 > 20.0f) ? pv0 : 0.0f;  // sf.fire: strictly greater
        const float th1 = (pv1 > 20.0f) ? pv1 : 0.0f;
        thr_s[(o2 >> 5) * 33 + (o2 & 31)]             = th0;
        thr_s[((o2 + 1) >> 5) * 33 + ((o2 + 1) & 31)] = th1;
    }
    __syncthreads();

    // ---- kWTA (verified logic, unchanged)
    if (tid < 32) {
        const int k = tid;
        int ns = 0;
        for (int t = 0; t < 32; ++t) ns += (thr_s[t * 33 + k] > 0.0f) ? 1 : 0;
        int first = 32 - ns; if (first > 31) first = 31;   // clip(T - nspk, 0, T-1)
        const float vf = thr_s[first * 33 + k];
        nspk_s[k] = (float)ns;
        vals_s[k] = vf;
        cand_s[k] = (ns > 0) ? vf : 0.0f;                  // max_t spikes*vals per k
        mask_s[k] = 0.0f;
    }
    __syncthreads();

    if (tid == 0) {
        float vm = 0.0f;
        for (int k = 0; k < 32; ++k) vm = fmaxf(vm, cand_s[k]);
        const float v = vm * 32.0f;                        // trunc.max() * T
        for (int k = 0; k < 32; ++k) tot_s[k] = nspk_s[k] * (vals_s[k] + v);
        // top-4, ties -> lower index (matches lax.top_k); winner valid iff total != 0
        for (int sel = 0; sel < 4; ++sel) {
            int best = 0; float bv = -1.0f;
            for (int k = 0; k < 32; ++k) {
                const float tv = tot_s[k];
                if (tv > bv) { bv = tv; best = k; }
            }
            if (bv > 0.0f) mask_s[best] = 1.0f;
            tot_s[best] = -1.0f;
        }
    }
    __syncthreads();

#pragma unroll
    for (int e = 0; e < 2; ++e) {
        const int oo = o2 + e;
        const int t = oo >> 5, k = oo & 31;
        const float v = (thr_s[t * 33 + k] > 0.0f && mask_s[k] > 0.0f) ? 1.0f : 0.0f;
        __builtin_nontemporal_store(v, out + (size_t)t * (KN * RFN) + k * RFN + r);
    }
}

extern "C" void kernel_launch(void* const* d_in, const int* in_sizes, int n_in,
                              void* d_out, int out_size, void* d_ws, size_t ws_size,
                              hipStream_t stream) {
    const float* rec = (const float*)d_in[0];   // rec_field (32,1,512,2048)
    const float* wgt = (const float*)d_in[1];   // W         (512,32,1,2048)
    // d_in[2] = reward: unused by the forward output; d_ws: unused (fully fused)
    float* out = (float*)d_out;                 // (32,1,32,512)
    column1_fused<<<dim3(RFN), dim3(512), 0, stream>>>(rec, wgt, out);
}